// Round 6
// baseline (70.428 us; speedup 1.0000x reference)
//
#include <hip/hip_runtime.h>

// KDPointToPointLoss: B=8, C=3, N=M=4096, fp32.
// loss[b] = (1/(3N)) * sum_n [ s_n^2 + min_m (t_m^2 - 2 s_n . t_m) ]
//
// R6: R5 was grid-limited to 2 blocks/CU (16 waves = 50% occupancy) ->
// LDS-latency bubbles. Double grid: 1024 blocks (T=256 targets/block),
// 4 resident blocks/CU x 8 waves = 100% wave slots. Vectorized source
// prologue (8 contiguous sources/lane -> dwordx4).
//
// grid: 1024 blocks = 8 batches x 16 target-chunks x 8 source-groups.
// block: 512 thr (8 waves). Stage 256 targets (4KB) as (x,y,z,t^2);
// each wave sweeps its 32 targets vs 512 sources (8/lane, contiguous).
// Cross-wave min (+s^2) -> partial[chunk][b][src]; pass 2 min-combines
// 16 chunks, sums per batch.

#define B_ 8
#define N_ 4096
#define CH 4096
#define BS 12288
#define TQ 256           // targets per block
#define BIG 3.4e38f

__global__ __launch_bounds__(512, 8)    // 8 waves/EU -> 4 blocks/CU, VGPR<=64
void nn_loss_main(const float* __restrict__ src,
                  const float* __restrict__ tgt,
                  float* __restrict__ partial) {
    __shared__ __align__(16) char smem[8 * 512 * 4];  // 16 KB: stage(4K) / red(16K)
    float4* stage = (float4*)smem;
    float*  red   = (float*)smem;

    const int tid  = threadIdx.x;        // 0..511
    const int blk  = blockIdx.x;         // 0..1023
    const int b    = blk >> 7;           // 0..7
    const int c    = (blk >> 3) & 15;    // target chunk 0..15 (256 each)
    const int sgrp = blk & 7;            // source group 0..7 (512 each)
    const int ls   = tid & 63;
    const int w    = tid >> 6;           // wave 0..7

    // ---- stage this chunk's targets: (x,y,z, x^2+y^2+z^2) ----
    if (tid < TQ) {
        const float* tb = tgt + b * BS;
        const int m = (c << 8) + tid;
        float x = tb[m], y = tb[m + CH], z = tb[m + 2 * CH];
        stage[tid] = make_float4(x, y, z, x * x + y * y + z * z);
    }

    // ---- load 8 contiguous sources per lane (vectorized) ----
    const float* sbase = src + b * BS + (sgrp << 9) + (ls << 3);
    float4 xa = ((const float4*)sbase)[0];
    float4 xb = ((const float4*)sbase)[1];
    float4 ya = ((const float4*)(sbase + CH))[0];
    float4 yb = ((const float4*)(sbase + CH))[1];
    float4 za = ((const float4*)(sbase + 2 * CH))[0];
    float4 zb = ((const float4*)(sbase + 2 * CH))[1];

    float ax[8], ay[8], az[8];
    ax[0] = -2.0f * xa.x; ax[1] = -2.0f * xa.y; ax[2] = -2.0f * xa.z; ax[3] = -2.0f * xa.w;
    ax[4] = -2.0f * xb.x; ax[5] = -2.0f * xb.y; ax[6] = -2.0f * xb.z; ax[7] = -2.0f * xb.w;
    ay[0] = -2.0f * ya.x; ay[1] = -2.0f * ya.y; ay[2] = -2.0f * ya.z; ay[3] = -2.0f * ya.w;
    ay[4] = -2.0f * yb.x; ay[5] = -2.0f * yb.y; ay[6] = -2.0f * yb.z; ay[7] = -2.0f * yb.w;
    az[0] = -2.0f * za.x; az[1] = -2.0f * za.y; az[2] = -2.0f * za.z; az[3] = -2.0f * za.w;
    az[4] = -2.0f * zb.x; az[5] = -2.0f * zb.y; az[6] = -2.0f * zb.z; az[7] = -2.0f * zb.w;

    __syncthreads();

    // ---- sweep this wave's 32 targets against 512 sources ----
    float best[8];
    #pragma unroll
    for (int j = 0; j < 8; ++j) best[j] = BIG;

    const float4* tp = stage + (w << 5);
    #pragma unroll 4
    for (int i = 0; i < 32; i += 2) {
        float4 t0 = tp[i];
        float4 t1 = tp[i + 1];
        #pragma unroll
        for (int j = 0; j < 8; ++j) {
            float d0 = fmaf(ax[j], t0.x, fmaf(ay[j], t0.y, fmaf(az[j], t0.z, t0.w)));
            float d1 = fmaf(ax[j], t1.x, fmaf(ay[j], t1.y, fmaf(az[j], t1.z, t1.w)));
            best[j] = fminf(fminf(best[j], d0), d1);   // v_min3_f32
        }
    }

    __syncthreads();   // staging reads done; reuse smem as red[8][512]

    // store best + s^2  (s^2 = 0.25*(ax^2+ay^2+az^2), exact pow2 scale)
    #pragma unroll
    for (int j = 0; j < 8; ++j) {
        float s2 = 0.25f * fmaf(ax[j], ax[j], fmaf(ay[j], ay[j], az[j] * az[j]));
        red[(w << 9) + (ls << 3) + j] = best[j] + s2;
    }

    __syncthreads();

    // combine across 8 waves; thread tid handles block-source tid
    float mn = red[tid];
    #pragma unroll
    for (int v = 1; v < 8; ++v)
        mn = fminf(mn, red[(v << 9) + tid]);
    partial[(c << 15) + (b << 12) + (sgrp << 9) + tid] = mn;
}

// ---- pass 2: min over 16 chunks per source, sum per batch ----
__global__ __launch_bounds__(1024)
void reduce_kernel(const float* __restrict__ partial,
                   float* __restrict__ out) {
    const int b = blockIdx.x;            // 0..7
    const int tid = threadIdx.x;         // 0..1023

    float acc = 0.0f;
    #pragma unroll
    for (int j = 0; j < 4; ++j) {
        int base = (b << 12) + (j << 10) + tid;
        float mn = partial[base];
        #pragma unroll
        for (int c = 1; c < 16; ++c)
            mn = fminf(mn, partial[(c << 15) + base]);
        acc += mn;
    }

    #pragma unroll
    for (int off = 32; off > 0; off >>= 1)
        acc += __shfl_down(acc, off, 64);

    __shared__ float red[16];
    if ((tid & 63) == 0) red[tid >> 6] = acc;
    __syncthreads();
    if (tid == 0) {
        float v = 0.0f;
        #pragma unroll
        for (int k = 0; k < 16; ++k) v += red[k];
        out[b] = v * (1.0f / (3.0f * (float)N_));
    }
}

extern "C" void kernel_launch(void* const* d_in, const int* in_sizes, int n_in,
                              void* d_out, int out_size, void* d_ws, size_t ws_size,
                              hipStream_t stream) {
    const float* src = (const float*)d_in[0];   // [8,3,4096]
    const float* tgt = (const float*)d_in[1];   // [8,3,4096]
    float* out = (float*)d_out;                 // [8]
    float* partial = (float*)d_ws;              // 16*8*4096 floats = 2 MB

    nn_loss_main<<<1024, 512, 0, stream>>>(src, tgt, partial);
    reduce_kernel<<<B_, 1024, 0, stream>>>(partial, out);
}

// Round 7
// 68.228 us; speedup vs baseline: 1.0322x; 1.0322x over previous
//
#include <hip/hip_runtime.h>

// KDPointToPointLoss: B=8, C=3, N=M=4096, fp32.
// loss[b] = (1/(3N)) * sum_n [ s_n^2 + min_m (t_m^2 - 2 s_n . t_m) ]
//
// R7: maximize per-block amortization. 256 blocks = 1/CU, each block:
// 1024 sources (16/lane) x 512 targets. Per 2 targets: 2 broadcast
// ds_read_b128 + 112 VALU (96 fma + 16 min3) -> VALU-bound at ~14.3K
// cyc/CU ~= 6us. Each wave stages+sweeps its OWN 64 targets, so no
// pre-sweep barrier. Epilogue: conflict-free LDS cross-wave min, slot-
// ordered coalesced partial write; reduce min-combines the 8 target-
// eighths per slot then sums (source identity never needed).

#define B_ 8
#define N_ 4096
#define CH 4096
#define BS 12288
#define BIG 3.4e38f

__global__ __launch_bounds__(512, 4)   // 4 waves/EU -> VGPR<=128, 2 blk/CU cap
void nn_loss_main(const float* __restrict__ src,
                  const float* __restrict__ tgt,
                  float* __restrict__ partial) {
    __shared__ __align__(16) char smem[8 * 1024 * 4];  // 32 KB: stage(8K)/red(32K)
    float4* stage = (float4*)smem;
    float*  red   = (float*)smem;

    const int tid  = threadIdx.x;        // 0..511
    const int blk  = blockIdx.x;         // 0..255
    const int b    = blk >> 5;           // 0..7
    const int e    = (blk >> 2) & 7;     // target eighth 0..7 (512 tgts)
    const int sgrp = blk & 3;            // source group 0..3 (1024 srcs)
    const int ls   = tid & 63;
    const int w    = tid >> 6;           // wave 0..7

    // ---- stage targets: thread tid stages target (e*512 + tid) ----
    // wave w stages exactly stage[64w..64w+64) and sweeps exactly that
    // region -> no cross-wave dependency, no barrier needed before sweep.
    {
        const float* tb = tgt + b * BS;
        const int m = (e << 9) + tid;
        float x = tb[m], y = tb[m + CH], z = tb[m + 2 * CH];
        stage[tid] = make_float4(x, y, z, x * x + y * y + z * z);
    }

    // ---- load 16 contiguous sources per lane (12x dwordx4) ----
    const float* sbase = src + b * BS + (sgrp << 10) + (ls << 4);
    float ax[16], ay[16], az[16];
    #pragma unroll
    for (int v = 0; v < 4; ++v) {
        float4 xx = ((const float4*)sbase)[v];
        float4 yy = ((const float4*)(sbase + CH))[v];
        float4 zz = ((const float4*)(sbase + 2 * CH))[v];
        ax[4*v+0] = -2.0f*xx.x; ax[4*v+1] = -2.0f*xx.y; ax[4*v+2] = -2.0f*xx.z; ax[4*v+3] = -2.0f*xx.w;
        ay[4*v+0] = -2.0f*yy.x; ay[4*v+1] = -2.0f*yy.y; ay[4*v+2] = -2.0f*yy.z; ay[4*v+3] = -2.0f*yy.w;
        az[4*v+0] = -2.0f*zz.x; az[4*v+1] = -2.0f*zz.y; az[4*v+2] = -2.0f*zz.z; az[4*v+3] = -2.0f*zz.w;
    }

    // ---- sweep this wave's 64 targets against 1024 sources ----
    float best[16];
    #pragma unroll
    for (int j = 0; j < 16; ++j) best[j] = BIG;

    const float4* tp = stage + (w << 6);
    #pragma unroll 2
    for (int i = 0; i < 64; i += 2) {
        float4 t0 = tp[i];
        float4 t1 = tp[i + 1];
        #pragma unroll
        for (int j = 0; j < 16; ++j) {
            float d0 = fmaf(ax[j], t0.x, fmaf(ay[j], t0.y, fmaf(az[j], t0.z, t0.w)));
            float d1 = fmaf(ax[j], t1.x, fmaf(ay[j], t1.y, fmaf(az[j], t1.z, t1.w)));
            best[j] = fminf(fminf(best[j], d0), d1);   // v_min3_f32
        }
    }

    __syncthreads();   // all waves done reading stage; reuse smem as red[8][1024]

    // red[w][j*64+ls]: lane-stride 4B -> conflict-free. slot = j*64+ls.
    // (slot->source mapping is wave-invariant; reduce never needs it.)
    #pragma unroll
    for (int j = 0; j < 16; ++j) {
        float s2 = 0.25f * fmaf(ax[j], ax[j], fmaf(ay[j], ay[j], az[j] * az[j]));
        red[(w << 10) + (j << 6) + ls] = best[j] + s2;
    }

    __syncthreads();

    // cross-wave min; thread tid handles slots tid and tid+512; coalesced.
    #pragma unroll
    for (int h = 0; h < 2; ++h) {
        int slot = (h << 9) + tid;
        float mn = red[slot];
        #pragma unroll
        for (int v = 1; v < 8; ++v)
            mn = fminf(mn, red[(v << 10) + slot]);
        partial[(e << 15) + (b << 12) + (sgrp << 10) + slot] = mn;
    }
}

// ---- pass 2: min over 8 eighths per slot, sum per batch ----
__global__ __launch_bounds__(1024)
void reduce_kernel(const float* __restrict__ partial,
                   float* __restrict__ out) {
    const int b = blockIdx.x;            // 0..7
    const int tid = threadIdx.x;         // 0..1023

    float acc = 0.0f;
    #pragma unroll
    for (int g = 0; g < 4; ++g) {        // source groups
        int base = (b << 12) + (g << 10) + tid;
        float mn = partial[base];
        #pragma unroll
        for (int e = 1; e < 8; ++e)
            mn = fminf(mn, partial[(e << 15) + base]);
        acc += mn;
    }

    #pragma unroll
    for (int off = 32; off > 0; off >>= 1)
        acc += __shfl_down(acc, off, 64);

    __shared__ float red[16];
    if ((tid & 63) == 0) red[tid >> 6] = acc;
    __syncthreads();
    if (tid == 0) {
        float v = 0.0f;
        #pragma unroll
        for (int k = 0; k < 16; ++k) v += red[k];
        out[b] = v * (1.0f / (3.0f * (float)N_));
    }
}

extern "C" void kernel_launch(void* const* d_in, const int* in_sizes, int n_in,
                              void* d_out, int out_size, void* d_ws, size_t ws_size,
                              hipStream_t stream) {
    const float* src = (const float*)d_in[0];   // [8,3,4096]
    const float* tgt = (const float*)d_in[1];   // [8,3,4096]
    float* out = (float*)d_out;                 // [8]
    float* partial = (float*)d_ws;              // 8*8*4*1024 floats = 1 MB

    nn_loss_main<<<256, 512, 0, stream>>>(src, tgt, partial);
    reduce_kernel<<<B_, 1024, 0, stream>>>(partial, out);
}